// Round 2
// baseline (369.220 us; speedup 1.0000x reference)
//
#include <hip/hip_runtime.h>

typedef unsigned int uu32;

#define NN 14      // nodes
#define FD 24      // SEQ / feature dim
#define HD 64      // GAT hidden
#define NE 70      // 56 edges + 14 self loops
#define BB 32768   // batch
#define SPW 4      // samples per wave
#define WPB 4      // waves per block
#define K1_BLOCKS (BB / (WPB * SPW))   // 2048
#define R2 2       // rows per thread in mlp_k
#define K2_BLOCKS (NN * (BB / (256 * R2)))   // 896
#define HAP 68     // padded row stride for H1/A1 (16B-aligned rows)
#define H2P 28     // padded row stride for H2 (16B-aligned rows)
#define PSZ 224    // dense P rows: 14*16

// Wave-local LDS sync: each wave owns a private LDS slice inside the sample
// loop; s_waitcnt lgkmcnt(0) + memory clobber orders this wave's ds ops.
#define WSYNC() asm volatile("s_waitcnt lgkmcnt(0)" ::: "memory")

// GAT stage: G = conv2(elu(conv1(x))) -> Gout[14][B][24] f32 (Gout == d_out;
// the MLP kernel rewrites d_out in place afterwards).
// X is consumed via the SCALAR path: the whole wave works on one sample, so
// x[b][f][n] addresses are wave-uniform -> readfirstlane the base and let
// hipcc emit s_load batches. This removes the old stage-1 LDS staging and
// all 84 broadcast ds_read_b128 of stage 2 (the LDS pipe is the measured
// binding resource at ~13 cy per b128, broadcast or not).
__global__ __launch_bounds__(256) void gat_k(
    const float* __restrict__ x, const int* __restrict__ ei,
    const float* __restrict__ W1, const float* __restrict__ as1,
    const float* __restrict__ ad1, const float* __restrict__ b1,
    const float* __restrict__ W2, const float* __restrict__ as2,
    const float* __restrict__ ad2, const float* __restrict__ b2,
    float* __restrict__ Gout) {
    __shared__ __align__(16) float HA[WPB][NN * HAP];   // H1 then A1 (952)
    __shared__ __align__(16) float H2S[WPB][NN * H2P];  // 392
    __shared__ __align__(16) float PS[WPB][PSZ];        // unnormalized exp rows
    __shared__ float sdS[WPB][2 * NN];                  // src/dst dots
    __shared__ float smS[WPB][NN];                      // per-dst exp sums
    __shared__ __align__(16) float a1S[2 * HD];
    __shared__ __align__(16) float a2S[2 * FD];
    __shared__ int esS[NE], edS[NE];

    const int tid = threadIdx.x;
    const int wv = tid >> 6;
    const int lane = tid & 63;
    float* HAw = HA[wv];
    float* H2w = H2S[wv];
    float* Pw = PS[wv];
    float* sdw = sdS[wv];
    float* smw = smS[wv];

    if (tid < 2 * HD) a1S[tid] = (tid < HD) ? as1[tid] : ad1[tid - HD];
    if (tid < 2 * FD) a2S[tid] = (tid < FD) ? as2[tid] : ad2[tid - FD];
    // edge staging: robust to int64 (lo/hi dword pairs) or int32 delivery
    if (tid < 56) {
        int e64 = 1;
        for (int i = 0; i < 8; i++)
            if (ei[2 * i + 1] != 0 || (uu32)ei[2 * i] >= (uu32)NN) e64 = 0;
        esS[tid] = e64 ? ei[2 * tid] : ei[tid];
        edS[tid] = e64 ? ei[112 + 2 * tid] : ei[56 + tid];
    } else if (tid < NE) {
        esS[tid] = tid - 56;   // self loops
        edS[tid] = tid - 56;
    }

    // per-lane resident weights
    float w1r[FD];
#pragma unroll
    for (int f = 0; f < FD; f++) w1r[f] = W1[f * HD + lane];
    const float b1r = b1[lane];
    const int f2 = lane % FD;
    const int g2 = lane / FD;      // 0,1 active for 24-wide stages
    float w2r[HD];
#pragma unroll
    for (int k = 0; k < HD; k++) w2r[k] = W2[k * FD + f2];
    const float b2r = b2[f2];
    __syncthreads();   // the ONE block barrier: cross-wave staged a1S/a2S/es/ed
    // edge ownership: edge0 = lane (0..63); lanes 0..5 also own 64..69
    const bool ex = (lane < NE - 64);
    const int s0 = esS[lane], d0 = edS[lane];
    const int s1 = esS[ex ? 64 + lane : 0], d1 = edS[ex ? 64 + lane : 0];

    const int gw = blockIdx.x * WPB + wv;
    for (int t = 0; t < SPW; t++) {
        const int b = gw * SPW + t;
        // wave-uniform X base -> SGPR; loads below become s_load batches
        const int bo = __builtin_amdgcn_readfirstlane(b * (NN * FD));
        const float* __restrict__ xb = x + bo;
        // ---- 2. H1 = X @ W1 (lane owns hidden col `lane`), X via SGPRs ----
        float acc[NN];
#pragma unroll
        for (int n = 0; n < NN; n++) acc[n] = 0.0f;
#pragma unroll
        for (int f = 0; f < FD; f++) {
            const float wf = w1r[f];
#pragma unroll
            for (int n = 0; n < NN; n++)
                acc[n] = fmaf(xb[f * NN + n], wf, acc[n]);   // x[b][f][n]
        }
#pragma unroll
        for (int n = 0; n < NN; n++) HAw[n * HAP + lane] = acc[n];
        WSYNC();
        // ---- 3. src/dst dots (28 lanes) + zero P/sums ----
        if (lane < 2 * NN) {
            const int v = (lane >= NN) ? 1 : 0;
            const int n2 = lane - v * NN;
            float s = 0.0f;
#pragma unroll
            for (int k = 0; k < 16; k++) {
                float4 h4 = *(const float4*)&HAw[n2 * HAP + 4 * k];
                float4 a4 = *(const float4*)&a1S[v * HD + 4 * k];
                s = fmaf(h4.x, a4.x, s); s = fmaf(h4.y, a4.y, s);
                s = fmaf(h4.z, a4.z, s); s = fmaf(h4.w, a4.w, s);
            }
            sdw[v * NN + n2] = s;
        }
        if (lane < PSZ / 4)
            *(float4*)&Pw[lane * 4] = make_float4(0.f, 0.f, 0.f, 0.f);
        if (lane < NN) smw[lane] = 0.0f;
        WSYNC();
        // ---- 4. softmax1 (shift-invariant, no max pass: |alpha| << 88) ----
        {
            float a = sdw[s0] + sdw[NN + d0];
            a = a > 0.0f ? a : 0.2f * a;               // leaky_relu(0.2)
            float e0 = __expf(a);
            atomicAdd(&smw[d0], e0);
            atomicAdd(&Pw[d0 * 16 + s0], e0);          // unnormalized
            if (ex) {
                a = sdw[s1] + sdw[NN + d1];
                a = a > 0.0f ? a : 0.2f * a;
                float e1 = __expf(a);
                atomicAdd(&smw[d1], e1);
                atomicAdd(&Pw[d1 * 16 + s1], e1);
            }
        }
        WSYNC();
        // ---- 5. A1 = ELU(P @ H1 / sum + b1); H1 from regs; write to HA ----
        float acc2[NN];
#pragma unroll
        for (int n = 0; n < NN; n++) {
            float a = 0.0f;
#pragma unroll
            for (int k4 = 0; k4 < 3; k4++) {
                float4 p4 = *(const float4*)&Pw[n * 16 + 4 * k4];   // broadcast
                a = fmaf(p4.x, acc[4 * k4 + 0], a);
                a = fmaf(p4.y, acc[4 * k4 + 1], a);
                a = fmaf(p4.z, acc[4 * k4 + 2], a);
                a = fmaf(p4.w, acc[4 * k4 + 3], a);
            }
            float4 p4 = *(const float4*)&Pw[n * 16 + 12];
            a = fmaf(p4.x, acc[12], a);
            a = fmaf(p4.y, acc[13], a);
            a = __fdividef(a, smw[n]) + b1r;
            acc2[n] = a > 0.0f ? a : (__expf(a) - 1.0f);   // ELU
        }
#pragma unroll
        for (int n = 0; n < NN; n++) HAw[n * HAP + lane] = acc2[n];
        WSYNC();
        // ---- 6. H2 = A1 @ W2 : lane (g2,f2) covers 7 nodes ----
        if (g2 < 2) {
#pragma unroll
            for (int i = 0; i < 7; i++) {
                const int n = g2 + 2 * i;
                float a = 0.0f;
#pragma unroll
                for (int k4 = 0; k4 < 16; k4++) {
                    float4 v4 = *(const float4*)&HAw[n * HAP + 4 * k4];
                    a = fmaf(v4.x, w2r[4 * k4 + 0], a);
                    a = fmaf(v4.y, w2r[4 * k4 + 1], a);
                    a = fmaf(v4.z, w2r[4 * k4 + 2], a);
                    a = fmaf(v4.w, w2r[4 * k4 + 3], a);
                }
                H2w[n * H2P + f2] = a;
            }
        }
        WSYNC();
        // ---- 7. conv2 dots (28 lanes) + zero P/sums ----
        if (lane < 2 * NN) {
            const int v = (lane >= NN) ? 1 : 0;
            const int n2 = lane - v * NN;
            float s = 0.0f;
#pragma unroll
            for (int q = 0; q < 6; q++) {
                float4 h4 = *(const float4*)&H2w[n2 * H2P + 4 * q];
                float4 a4 = *(const float4*)&a2S[v * FD + 4 * q];
                s = fmaf(h4.x, a4.x, s); s = fmaf(h4.y, a4.y, s);
                s = fmaf(h4.z, a4.z, s); s = fmaf(h4.w, a4.w, s);
            }
            sdw[v * NN + n2] = s;
        }
        if (lane < PSZ / 4)
            *(float4*)&Pw[lane * 4] = make_float4(0.f, 0.f, 0.f, 0.f);
        if (lane < NN) smw[lane] = 0.0f;
        WSYNC();
        // ---- 8. softmax2 ----
        {
            float a = sdw[s0] + sdw[NN + d0];
            a = a > 0.0f ? a : 0.2f * a;
            float e0 = __expf(a);
            atomicAdd(&smw[d0], e0);
            atomicAdd(&Pw[d0 * 16 + s0], e0);
            if (ex) {
                a = sdw[s1] + sdw[NN + d1];
                a = a > 0.0f ? a : 0.2f * a;
                float e1 = __expf(a);
                atomicAdd(&smw[d1], e1);
                atomicAdd(&Pw[d1 * 16 + s1], e1);
            }
        }
        WSYNC();
        // ---- 9. G = P2 @ H2 / sum + b2 -> d_out [14][B][24] ----
        if (g2 < 2) {
            float h2c[NN];
#pragma unroll
            for (int k = 0; k < NN; k++) h2c[k] = H2w[k * H2P + f2];
#pragma unroll
            for (int i = 0; i < 7; i++) {
                const int n = g2 + 2 * i;
                float a = 0.0f;
#pragma unroll
                for (int k4 = 0; k4 < 3; k4++) {
                    float4 p4 = *(const float4*)&Pw[n * 16 + 4 * k4];
                    a = fmaf(p4.x, h2c[4 * k4 + 0], a);
                    a = fmaf(p4.y, h2c[4 * k4 + 1], a);
                    a = fmaf(p4.z, h2c[4 * k4 + 2], a);
                    a = fmaf(p4.w, h2c[4 * k4 + 3], a);
                }
                float4 p4 = *(const float4*)&Pw[n * 16 + 12];
                a = fmaf(p4.x, h2c[12], a);
                a = fmaf(p4.y, h2c[13], a);
                Gout[((size_t)n * BB + b) * FD + f2] =
                    __fdividef(a, smw[n]) + b2r;
            }
        }
        WSYNC();   // protect reused LDS before next sample (wave-local)
    }
}

// MLP stage, in place on d_out. LDS-broadcast weights (the scalar-path
// variant regressed: SMEM is unordered so every use forces lgkmcnt(0) full
// drains). Each thread now owns TWO rows, so every weight ds_read_b128
// feeds 8 FMAs instead of 4 -> total ds instructions (the measured binding
// resource at ~13 cy each on the CU LDS pipe) halve.
__global__ __launch_bounds__(256) void mlp_k(
    const float* __restrict__ fc1w, const float* __restrict__ fc1b,
    const float* __restrict__ fc2w, const float* __restrict__ fc2b,
    float* __restrict__ gio) {
    __shared__ __align__(16) float W1L[FD * HD];
    __shared__ __align__(16) float W2L[HD * FD];
    __shared__ float B1L[HD];
    __shared__ float B2L[FD];

    const int t = threadIdx.x;
    const int n = blockIdx.x >> 6;             // 64 blocks per node
    const int b0 = (blockIdx.x & 63) * 512;    // 512 rows per block

    const float4* w1p = (const float4*)(fc1w + (size_t)n * (FD * HD));
    const float4* w2p = (const float4*)(fc2w + (size_t)n * (HD * FD));
    for (int i = t; i < 384; i += 256) {
        *(float4*)&W1L[4 * i] = w1p[i];
        *(float4*)&W2L[4 * i] = w2p[i];
    }
    if (t < HD) B1L[t] = fc1b[n * HD + t];
    if (t < FD) B2L[t] = fc2b[n * FD + t];
    __syncthreads();

    const size_t base0 = ((size_t)n * BB + b0 + t) * FD;
    const size_t base1 = base0 + (size_t)256 * FD;
    float g0[FD], g1[FD], o0[FD], o1[FD];
#pragma unroll
    for (int q = 0; q < 6; q++) {
        *(float4*)&g0[4 * q] = *(const float4*)&gio[base0 + 4 * q];
        *(float4*)&g1[4 * q] = *(const float4*)&gio[base1 + 4 * q];
    }
#pragma unroll
    for (int f = 0; f < FD; f++) { o0[f] = B2L[f]; o1[f] = o0[f]; }

#pragma unroll 1   // keep hot loop I$-resident (~3.5 KB)
    for (int j4 = 0; j4 < 16; j4++) {
        float h00 = B1L[4 * j4 + 0], h01 = B1L[4 * j4 + 1];
        float h02 = B1L[4 * j4 + 2], h03 = B1L[4 * j4 + 3];
        float h10 = h00, h11 = h01, h12 = h02, h13 = h03;
#pragma unroll
        for (int f = 0; f < FD; f++) {
            float4 w4 = *(const float4*)&W1L[f * HD + 4 * j4];   // broadcast
            h00 = fmaf(g0[f], w4.x, h00); h01 = fmaf(g0[f], w4.y, h01);
            h02 = fmaf(g0[f], w4.z, h02); h03 = fmaf(g0[f], w4.w, h03);
            h10 = fmaf(g1[f], w4.x, h10); h11 = fmaf(g1[f], w4.y, h11);
            h12 = fmaf(g1[f], w4.z, h12); h13 = fmaf(g1[f], w4.w, h13);
        }
        h00 = fmaxf(h00, 0.f); h01 = fmaxf(h01, 0.f);
        h02 = fmaxf(h02, 0.f); h03 = fmaxf(h03, 0.f);
        h10 = fmaxf(h10, 0.f); h11 = fmaxf(h11, 0.f);
        h12 = fmaxf(h12, 0.f); h13 = fmaxf(h13, 0.f);
        float hv0[4] = {h00, h01, h02, h03};
        float hv1[4] = {h10, h11, h12, h13};
#pragma unroll
        for (int u2 = 0; u2 < 4; u2++) {
            const int j = 4 * j4 + u2;
#pragma unroll
            for (int f4 = 0; f4 < 6; f4++) {
                float4 w4 = *(const float4*)&W2L[j * FD + 4 * f4];   // broadcast
                o0[4 * f4 + 0] = fmaf(hv0[u2], w4.x, o0[4 * f4 + 0]);
                o0[4 * f4 + 1] = fmaf(hv0[u2], w4.y, o0[4 * f4 + 1]);
                o0[4 * f4 + 2] = fmaf(hv0[u2], w4.z, o0[4 * f4 + 2]);
                o0[4 * f4 + 3] = fmaf(hv0[u2], w4.w, o0[4 * f4 + 3]);
                o1[4 * f4 + 0] = fmaf(hv1[u2], w4.x, o1[4 * f4 + 0]);
                o1[4 * f4 + 1] = fmaf(hv1[u2], w4.y, o1[4 * f4 + 1]);
                o1[4 * f4 + 2] = fmaf(hv1[u2], w4.z, o1[4 * f4 + 2]);
                o1[4 * f4 + 3] = fmaf(hv1[u2], w4.w, o1[4 * f4 + 3]);
            }
        }
    }
#pragma unroll
    for (int q = 0; q < 6; q++) {
        *(float4*)&gio[base0 + 4 * q] = *(const float4*)&o0[4 * q];
        *(float4*)&gio[base1 + 4 * q] = *(const float4*)&o1[4 * q];
    }
}

extern "C" void kernel_launch(void* const* d_in, const int* in_sizes, int n_in,
                              void* d_out, int out_size, void* d_ws, size_t ws_size,
                              hipStream_t stream) {
    (void)in_sizes; (void)n_in; (void)out_size; (void)d_ws; (void)ws_size;
    const float* x    = (const float*)d_in[0];
    const int*   ei   = (const int*)d_in[1];
    const float* W1   = (const float*)d_in[2];
    const float* as1  = (const float*)d_in[3];
    const float* ad1  = (const float*)d_in[4];
    const float* b1   = (const float*)d_in[5];
    const float* W2   = (const float*)d_in[6];
    const float* as2  = (const float*)d_in[7];
    const float* ad2  = (const float*)d_in[8];
    const float* b2   = (const float*)d_in[9];
    const float* fc1w = (const float*)d_in[10];
    const float* fc1b = (const float*)d_in[11];
    const float* fc2w = (const float*)d_in[12];
    const float* fc2b = (const float*)d_in[13];
    float* gio = (float*)d_out;   // G staged in d_out, MLP rewrites in place

    gat_k<<<dim3(K1_BLOCKS), dim3(256), 0, stream>>>(
        x, ei, W1, as1, ad1, b1, W2, as2, ad2, b2, gio);
    mlp_k<<<dim3(K2_BLOCKS), dim3(256), 0, stream>>>(
        fc1w, fc1b, fc2w, fc2b, gio);
}

// Round 3
// 367.896 us; speedup vs baseline: 1.0036x; 1.0036x over previous
//
#include <hip/hip_runtime.h>

typedef unsigned int uu32;

#define NN 14      // nodes
#define FD 24      // SEQ / feature dim
#define HD 64      // GAT hidden
#define NE 70      // 56 edges + 14 self loops
#define BB 32768   // batch
#define SPW 4      // samples per wave
#define WPB 4      // waves per block
#define K1_BLOCKS (BB / (WPB * SPW))   // 2048
#define R2 2       // rows per thread in mlp_k
#define K2_BLOCKS (NN * (BB / (256 * R2)))   // 896
#define HAP 68     // padded row stride for H1/A1 (16B-aligned rows)
#define H2P 24     // row stride for H2 (96B rows, 16B-aligned)
#define PSZ 224    // dense P rows: 14*16

// Wave-local LDS sync (each wave owns a private slice inside the loop).
#define WSYNC() asm volatile("s_waitcnt lgkmcnt(0)" ::: "memory")

// readlane: pure-VALU wave broadcast (no LDS pipe, no lgkmcnt).
__device__ __forceinline__ float rdl(float v, int l) {
    union { float f; int i; } u;
    u.f = v;
    u.i = __builtin_amdgcn_readlane(u.i, l);
    return u.f;
}

// GAT stage. The per-CU LDS pipe (shared by 4 SIMDs, ~13 cy per b128 even
// for broadcast addresses) was the measured binder; all wave-uniform
// broadcasts that can move to registers now go through v_readlane instead.
__global__ __launch_bounds__(256) void gat_k(
    const float* __restrict__ x, const int* __restrict__ ei,
    const float* __restrict__ W1, const float* __restrict__ as1,
    const float* __restrict__ ad1, const float* __restrict__ b1,
    const float* __restrict__ W2, const float* __restrict__ as2,
    const float* __restrict__ ad2, const float* __restrict__ b2,
    float* __restrict__ Gout) {
    __shared__ __align__(16) float HA[WPB][NN * HAP];   // H1 then A1
    __shared__ __align__(16) float H2S[WPB][NN * H2P];
    __shared__ __align__(16) float PS[WPB][PSZ];        // unnormalized exp rows
    __shared__ float sdS[WPB][2 * NN];                  // src/dst dots
    __shared__ float smS[WPB][NN];                      // per-dst exp sums
    __shared__ __align__(16) float a1S[2 * HD];
    __shared__ __align__(16) float a2S[2 * FD];
    __shared__ int esS[NE], edS[NE];

    const int tid = threadIdx.x;
    const int wv = tid >> 6;
    const int lane = tid & 63;
    float* HAw = HA[wv];
    float* H2w = H2S[wv];
    float* Pw = PS[wv];
    float* sdw = sdS[wv];
    float* smw = smS[wv];

    if (tid < 2 * HD) a1S[tid] = (tid < HD) ? as1[tid] : ad1[tid - HD];
    if (tid < 2 * FD) a2S[tid] = (tid < FD) ? as2[tid] : ad2[tid - FD];
    // edge staging: robust to int64 (lo/hi dword pairs) or int32 delivery
    if (tid < 56) {
        int e64 = 1;
        for (int i = 0; i < 8; i++)
            if (ei[2 * i + 1] != 0 || (uu32)ei[2 * i] >= (uu32)NN) e64 = 0;
        esS[tid] = e64 ? ei[2 * tid] : ei[tid];
        edS[tid] = e64 ? ei[112 + 2 * tid] : ei[56 + tid];
    } else if (tid < NE) {
        esS[tid] = tid - 56;   // self loops
        edS[tid] = tid - 56;
    }

    // per-lane resident weights
    float w1r[FD];
#pragma unroll
    for (int f = 0; f < FD; f++) w1r[f] = W1[f * HD + lane];
    const float b1r = b1[lane];
    const int f2 = lane % FD;
    const int g2 = lane / FD;      // 0,1 active for 24-wide stages
    float w2r[HD];
#pragma unroll
    for (int k = 0; k < HD; k++) w2r[k] = W2[k * FD + f2];
    const float b2r = b2[f2];
    __syncthreads();   // the ONE block barrier: cross-wave staged a1S/a2S/es/ed
    // edge ownership: edge0 = lane (0..63); lanes 0..5 also own 64..69
    const bool ex = (lane < NE - 64);
    const int s0 = esS[lane], d0 = edS[lane];
    const int s1 = esS[ex ? 64 + lane : 0], d1 = edS[ex ? 64 + lane : 0];

    const int gw = blockIdx.x * WPB + wv;
#pragma unroll 1
    for (int t = 0; t < SPW; t++) {
        const size_t b = (size_t)gw * SPW + t;
        // ---- 1. X[b] per-lane into regs (coalesced); no LDS staging ----
        const float* __restrict__ xb = x + b * (NN * FD);
        float xr[6];
        xr[0] = xb[lane];
        xr[1] = xb[64 + lane];
        xr[2] = xb[128 + lane];
        xr[3] = xb[192 + lane];
        xr[4] = xb[256 + lane];
        xr[5] = (lane < NN * FD - 320) ? xb[320 + lane] : 0.0f;
        // ---- 2. H1 = X @ W1 (lane owns hidden col); X via readlane ----
        float acc[NN];
#pragma unroll
        for (int n = 0; n < NN; n++) acc[n] = 0.0f;
#pragma unroll
        for (int f = 0; f < FD; f++) {
#pragma unroll
            for (int n = 0; n < NN; n++) {
                const int i = f * NN + n;          // compile-time
                acc[n] = fmaf(rdl(xr[i >> 6], i & 63), w1r[f], acc[n]);
            }
        }
#pragma unroll
        for (int n = 0; n < NN; n++) HAw[n * HAP + lane] = acc[n];
        WSYNC();
        // ---- 3. src/dst dots (28 lanes) + zero P/sums ----
        if (lane < 2 * NN) {
            const int v = (lane >= NN) ? 1 : 0;
            const int n2 = lane - v * NN;
            float s = 0.0f;
#pragma unroll
            for (int k = 0; k < 16; k++) {
                float4 h4 = *(const float4*)&HAw[n2 * HAP + 4 * k];
                float4 a4 = *(const float4*)&a1S[v * HD + 4 * k];
                s = fmaf(h4.x, a4.x, s); s = fmaf(h4.y, a4.y, s);
                s = fmaf(h4.z, a4.z, s); s = fmaf(h4.w, a4.w, s);
            }
            sdw[v * NN + n2] = s;
        }
        if (lane < PSZ / 4)
            *(float4*)&Pw[lane * 4] = make_float4(0.f, 0.f, 0.f, 0.f);
        if (lane < NN) smw[lane] = 0.0f;
        WSYNC();
        // ---- 4. softmax1 (shift-invariant, no max pass: |alpha| << 88) ----
        {
            float a = sdw[s0] + sdw[NN + d0];
            a = a > 0.0f ? a : 0.2f * a;               // leaky_relu(0.2)
            float e0 = __expf(a);
            atomicAdd(&smw[d0], e0);
            atomicAdd(&Pw[d0 * 16 + s0], e0);          // unnormalized
            if (ex) {
                a = sdw[s1] + sdw[NN + d1];
                a = a > 0.0f ? a : 0.2f * a;
                float e1 = __expf(a);
                atomicAdd(&smw[d1], e1);
                atomicAdd(&Pw[d1 * 16 + s1], e1);
            }
        }
        WSYNC();
        // ---- 5. A1 = ELU(P @ H1 / sum + b1); P gathered per-lane then
        //         broadcast via readlane (4 coalesced b32 instead of 56 b128)
        const float pr0 = Pw[lane];
        const float pr1 = Pw[64 + lane];
        const float pr2 = Pw[128 + lane];
        const float pr3 = (lane < PSZ - 192) ? Pw[192 + lane] : 0.0f;
        const float smr = (lane < NN) ? smw[lane] : 1.0f;
        float acc2[NN];
#pragma unroll
        for (int n = 0; n < NN; n++) {
            float a = 0.0f;
#pragma unroll
            for (int k = 0; k < NN; k++) {
                const int i = n * 16 + k;          // compile-time
                const float pv = (i < 64) ? rdl(pr0, i) :
                                 (i < 128) ? rdl(pr1, i - 64) :
                                 (i < 192) ? rdl(pr2, i - 128) :
                                             rdl(pr3, i - 192);
                a = fmaf(pv, acc[k], a);
            }
            a = __fdividef(a, rdl(smr, n)) + b1r;
            acc2[n] = a > 0.0f ? a : (__expf(a) - 1.0f);   // ELU
        }
#pragma unroll
        for (int n = 0; n < NN; n++) HAw[n * HAP + lane] = acc2[n];
        WSYNC();
        // ---- 6. H2 = A1 @ W2 : lane (g2,f2) covers 7 nodes ----
        if (g2 < 2) {
#pragma unroll
            for (int i = 0; i < 7; i++) {
                const int n = g2 + 2 * i;
                float a = 0.0f;
#pragma unroll
                for (int k4 = 0; k4 < 16; k4++) {
                    float4 v4 = *(const float4*)&HAw[n * HAP + 4 * k4];
                    a = fmaf(v4.x, w2r[4 * k4 + 0], a);
                    a = fmaf(v4.y, w2r[4 * k4 + 1], a);
                    a = fmaf(v4.z, w2r[4 * k4 + 2], a);
                    a = fmaf(v4.w, w2r[4 * k4 + 3], a);
                }
                H2w[n * H2P + f2] = a;
            }
        }
        WSYNC();
        // ---- 7. conv2 dots (28 lanes) + zero P/sums ----
        if (lane < 2 * NN) {
            const int v = (lane >= NN) ? 1 : 0;
            const int n2 = lane - v * NN;
            float s = 0.0f;
#pragma unroll
            for (int q = 0; q < 6; q++) {
                float4 h4 = *(const float4*)&H2w[n2 * H2P + 4 * q];
                float4 a4 = *(const float4*)&a2S[v * FD + 4 * q];
                s = fmaf(h4.x, a4.x, s); s = fmaf(h4.y, a4.y, s);
                s = fmaf(h4.z, a4.z, s); s = fmaf(h4.w, a4.w, s);
            }
            sdw[v * NN + n2] = s;
        }
        if (lane < PSZ / 4)
            *(float4*)&Pw[lane * 4] = make_float4(0.f, 0.f, 0.f, 0.f);
        if (lane < NN) smw[lane] = 0.0f;
        WSYNC();
        // ---- 8. softmax2 ----
        {
            float a = sdw[s0] + sdw[NN + d0];
            a = a > 0.0f ? a : 0.2f * a;
            float e0 = __expf(a);
            atomicAdd(&smw[d0], e0);
            atomicAdd(&Pw[d0 * 16 + s0], e0);
            if (ex) {
                a = sdw[s1] + sdw[NN + d1];
                a = a > 0.0f ? a : 0.2f * a;
                float e1 = __expf(a);
                atomicAdd(&smw[d1], e1);
                atomicAdd(&Pw[d1 * 16 + s1], e1);
            }
        }
        WSYNC();
        // ---- 9. G = P2 @ H2 / sum + b2 -> d_out [14][B][24] ----
        if (g2 < 2) {
            float h2c[NN];
#pragma unroll
            for (int k = 0; k < NN; k++) h2c[k] = H2w[k * H2P + f2];
#pragma unroll
            for (int i = 0; i < 7; i++) {
                const int n = g2 + 2 * i;
                float a = 0.0f;
#pragma unroll
                for (int k4 = 0; k4 < 3; k4++) {
                    float4 p4 = *(const float4*)&Pw[n * 16 + 4 * k4];
                    a = fmaf(p4.x, h2c[4 * k4 + 0], a);
                    a = fmaf(p4.y, h2c[4 * k4 + 1], a);
                    a = fmaf(p4.z, h2c[4 * k4 + 2], a);
                    a = fmaf(p4.w, h2c[4 * k4 + 3], a);
                }
                float4 p4 = *(const float4*)&Pw[n * 16 + 12];
                a = fmaf(p4.x, h2c[12], a);
                a = fmaf(p4.y, h2c[13], a);
                Gout[((size_t)n * BB + b) * FD + f2] =
                    __fdividef(a, smw[n]) + b2r;
            }
        }
        WSYNC();   // protect reused LDS before next sample (wave-local)
    }
}

// MLP stage, in place on d_out. ZERO LDS: lane l holds W1 column l and W2
// row l in VGPRs; the wave-shared weight value for each (j) is broadcast
// with v_readlane (pure VALU, SGPR result feeds v_fma's one SGPR operand).
// This takes the LDS pipe (the measured ~13 cy/inst shared bottleneck)
// entirely out of the loop. 2 rows/thread amortizes the readlane overhead.
__global__ __launch_bounds__(256) void mlp_k(
    const float* __restrict__ fc1w, const float* __restrict__ fc1b,
    const float* __restrict__ fc2w, const float* __restrict__ fc2b,
    float* __restrict__ gio) {
    const int t = threadIdx.x;
    const int lane = t & 63;
    const int n = blockIdx.x >> 6;             // 64 blocks per node
    const int b0 = (blockIdx.x & 63) * 512;    // 512 rows per block

    const float* __restrict__ W1n = fc1w + (size_t)n * (FD * HD);  // [24][64]
    const float* __restrict__ W2n = fc2w + (size_t)n * (HD * FD);  // [64][24]

    // lane l: W1 column l (coalesced, stride-256B rows), W2 row l
    float w1c[FD], w2r[FD];
#pragma unroll
    for (int f = 0; f < FD; f++) w1c[f] = W1n[f * HD + lane];
#pragma unroll
    for (int f = 0; f < FD; f++) w2r[f] = W2n[lane * FD + f];
    const float b1r = fc1b[(size_t)n * HD + lane];
    const float b2r = (lane < FD) ? fc2b[(size_t)n * FD + lane] : 0.0f;

    const size_t base0 = ((size_t)n * BB + b0 + t) * FD;
    const size_t base1 = base0 + (size_t)256 * FD;
    float g0[FD], g1[FD], o0[FD], o1[FD];
#pragma unroll
    for (int q = 0; q < 6; q++) {
        *(float4*)&g0[4 * q] = *(const float4*)&gio[base0 + 4 * q];
        *(float4*)&g1[4 * q] = *(const float4*)&gio[base1 + 4 * q];
    }
#pragma unroll
    for (int f = 0; f < FD; f++) {
        const float bv = rdl(b2r, f);
        o0[f] = bv; o1[f] = bv;
    }

#pragma unroll 1   // ~600 insts/iter, keep I$-resident
    for (int j4 = 0; j4 < 16; j4++) {
        float h0[4], h1[4];
#pragma unroll
        for (int u = 0; u < 4; u++) {
            const float bv = rdl(b1r, 4 * j4 + u);   // uniform runtime lane
            h0[u] = bv; h1[u] = bv;
        }
#pragma unroll
        for (int f = 0; f < FD; f++) {
            const float gf0 = g0[f], gf1 = g1[f];
#pragma unroll
            for (int u = 0; u < 4; u++) {
                const float w = rdl(w1c[f], 4 * j4 + u);
                h0[u] = fmaf(gf0, w, h0[u]);
                h1[u] = fmaf(gf1, w, h1[u]);
            }
        }
#pragma unroll
        for (int u = 0; u < 4; u++) {
            h0[u] = fmaxf(h0[u], 0.f);
            h1[u] = fmaxf(h1[u], 0.f);
        }
#pragma unroll
        for (int u = 0; u < 4; u++) {
            const float a0 = h0[u], a1 = h1[u];
#pragma unroll
            for (int f = 0; f < FD; f++) {
                const float w = rdl(w2r[f], 4 * j4 + u);
                o0[f] = fmaf(a0, w, o0[f]);
                o1[f] = fmaf(a1, w, o1[f]);
            }
        }
    }
#pragma unroll
    for (int q = 0; q < 6; q++) {
        *(float4*)&gio[base0 + 4 * q] = *(const float4*)&o0[4 * q];
        *(float4*)&gio[base1 + 4 * q] = *(const float4*)&o1[4 * q];
    }
}

extern "C" void kernel_launch(void* const* d_in, const int* in_sizes, int n_in,
                              void* d_out, int out_size, void* d_ws, size_t ws_size,
                              hipStream_t stream) {
    (void)in_sizes; (void)n_in; (void)out_size; (void)d_ws; (void)ws_size;
    const float* x    = (const float*)d_in[0];
    const int*   ei   = (const int*)d_in[1];
    const float* W1   = (const float*)d_in[2];
    const float* as1  = (const float*)d_in[3];
    const float* ad1  = (const float*)d_in[4];
    const float* b1   = (const float*)d_in[5];
    const float* W2   = (const float*)d_in[6];
    const float* as2  = (const float*)d_in[7];
    const float* ad2  = (const float*)d_in[8];
    const float* b2   = (const float*)d_in[9];
    const float* fc1w = (const float*)d_in[10];
    const float* fc1b = (const float*)d_in[11];
    const float* fc2w = (const float*)d_in[12];
    const float* fc2b = (const float*)d_in[13];
    float* gio = (float*)d_out;   // G staged in d_out, MLP rewrites in place

    gat_k<<<dim3(K1_BLOCKS), dim3(256), 0, stream>>>(
        x, ei, W1, as1, ad1, b1, W2, as2, ad2, b2, gio);
    mlp_k<<<dim3(K2_BLOCKS), dim3(256), 0, stream>>>(
        fc1w, fc1b, fc2w, fc2b, gio);
}